// Round 7
// baseline (1060.655 us; speedup 1.0000x reference)
//
#include <hip/hip_runtime.h>
#include <hip/hip_bf16.h>
#include <hip/hip_fp8.h>
#include <math.h>

#define N 8192
#define D 512
#define BM 256
#define BK 64
#define NSTRIP 32                       // N / BM
#define S_BLOCKS (NSTRIP * NSTRIP)      // 1024 S tiles
#define TRI (NSTRIP * (NSTRIP + 1) / 2) // 528
#define G_BLOCKS (2 * TRI)              // 1056 Gram tiles
#define SG_BLOCKS (S_BLOCKS + G_BLOCKS) // 2080

typedef float f32x16 __attribute__((ext_vector_type(16)));
typedef int i32x4 __attribute__((ext_vector_type(4)));
typedef int i32x8 __attribute__((ext_vector_type(8)));

__device__ inline void gload_lds16(const void* g, void* l) {
  __builtin_amdgcn_global_load_lds(
      (const __attribute__((address_space(1))) void*)g,
      (__attribute__((address_space(3))) void*)l, 16, 0, 0);
}

// ---------------- normalize to fp8 e4m3 + exact fp32 diagonal + zero out ----------------
// wave-per-row: 64 lanes x 8 floats = 512 = D; shuffle-only reduction, no barriers.
__global__ __launch_bounds__(256) void norm_kernel(
    const float* __restrict__ z1, const float* __restrict__ z2,
    unsigned char* __restrict__ q1, unsigned char* __restrict__ q2,
    float* __restrict__ diag, float* __restrict__ out) {
  int t = threadIdx.x;
  int lane = t & 63;
  int w = t >> 6;
  int row = blockIdx.x * 4 + w;
  if (blockIdx.x == 0 && t == 0) out[0] = 0.0f; // atomic target (stream-ordered)
  const float4* a = (const float4*)(z1 + (size_t)row * D);
  const float4* b = (const float4*)(z2 + (size_t)row * D);
  float4 xa0 = a[lane], xa1 = a[lane + 64];
  float4 xb0 = b[lane], xb1 = b[lane + 64];
  float ss1 = xa0.x * xa0.x + xa0.y * xa0.y + xa0.z * xa0.z + xa0.w * xa0.w +
              xa1.x * xa1.x + xa1.y * xa1.y + xa1.z * xa1.z + xa1.w * xa1.w;
  float ss2 = xb0.x * xb0.x + xb0.y * xb0.y + xb0.z * xb0.z + xb0.w * xb0.w +
              xb1.x * xb1.x + xb1.y * xb1.y + xb1.z * xb1.z + xb1.w * xb1.w;
  float dd = xa0.x * xb0.x + xa0.y * xb0.y + xa0.z * xb0.z + xa0.w * xb0.w +
             xa1.x * xb1.x + xa1.y * xb1.y + xa1.z * xb1.z + xa1.w * xb1.w;
#pragma unroll
  for (int off = 1; off < 64; off <<= 1) {
    ss1 += __shfl_xor(ss1, off);
    ss2 += __shfl_xor(ss2, off);
    dd  += __shfl_xor(dd,  off);
  }
  float i1 = 1.0f / fmaxf(sqrtf(ss1), 1e-12f);
  float i2 = 1.0f / fmaxf(sqrtf(ss2), 1e-12f);
  float fa[8] = {xa0.x, xa0.y, xa0.z, xa0.w, xa1.x, xa1.y, xa1.z, xa1.w};
  float fb[8] = {xb0.x, xb0.y, xb0.z, xb0.w, xb1.x, xb1.y, xb1.z, xb1.w};
  unsigned int u1[2], u2[2];
#pragma unroll
  for (int g = 0; g < 2; g++) {
    unsigned int v1 = 0, v2 = 0;
#pragma unroll
    for (int e = 0; e < 4; e++) {
      __hip_fp8_e4m3 c1(fa[g * 4 + e] * i1); // OCP e4m3fn
      __hip_fp8_e4m3 c2(fb[g * 4 + e] * i2);
      v1 |= ((unsigned int)c1.__x) << (8 * e);
      v2 |= ((unsigned int)c2.__x) << (8 * e);
    }
    u1[g] = v1; u2[g] = v2;
  }
  ((unsigned int*)q1)[(size_t)row * 128 + lane] = u1[0];
  ((unsigned int*)q1)[(size_t)row * 128 + 64 + lane] = u1[1];
  ((unsigned int*)q2)[(size_t)row * 128 + lane] = u2[0];
  ((unsigned int*)q2)[(size_t)row * 128 + 64 + lane] = u2[1];
  if (lane == 0) diag[row] = dd * i1 * i2;
}

// ---------------- stage one BK=64 chunk (A 16KB + B 16KB) into dbuf slot chunk&1 ------
// R5's measured-ZERO-conflict swizzle: LDS piece cs of row holds global piece
// cs ^ ((row>>1)&3) ^ ((row>>4)&1), folded into the per-thread global base
// (it-invariant: row passes step by 128, preserving both swizzle fields).
__device__ __forceinline__ void stage_chunk(
    const unsigned char* pA, const unsigned char* pB,
    unsigned char (*lds)[32768], int t, int chunk) {
  unsigned char* buf = lds[chunk & 1];
  int k0 = chunk * BK;
  gload_lds16(pA + k0,           buf + t * 16);          // A rows 0..127
  gload_lds16(pA + 128 * D + k0, buf + 8192 + t * 16);   // A rows 128..255
  gload_lds16(pB + k0,           buf + 16384 + t * 16);  // B rows 0..127
  gload_lds16(pB + 128 * D + k0, buf + 24576 + t * 16);  // B rows 128..255
}

// ---------------- one round: drain own stage, barrier, stage next, read, 8 MFMA -------
// R5-proven drain schedule (stage issued one full round before its drain). Ring-2
// reuse safety: stage(p+1) overwrites the buf whose ds_reads were lgkm-drained
// before round p-1's MFMAs, hence before barrier p.
#define SG_ROUND(p)                                                            \
  {                                                                            \
    asm volatile("s_waitcnt vmcnt(0)" ::: "memory");                           \
    __builtin_amdgcn_s_barrier();                                              \
    __builtin_amdgcn_sched_barrier(0);                                         \
    if ((p) < 7) stage_chunk(pA, pB, lds, t, (p) + 1);                         \
    const unsigned char* buf = lds[(p) & 1];                                   \
    i32x8 af[4], bf[2];                                                        \
    _Pragma("unroll")                                                          \
    for (int i = 0; i < 4; i++) {                                              \
      i32x4 lo = *(const i32x4*)(buf + offA[i]);                               \
      i32x4 hi = *(const i32x4*)(buf + (offA[i] ^ 16));                        \
      af[i] = __builtin_shufflevector(lo, hi, 0, 1, 2, 3, 4, 5, 6, 7);         \
    }                                                                          \
    _Pragma("unroll")                                                          \
    for (int j = 0; j < 2; j++) {                                              \
      i32x4 lo = *(const i32x4*)(buf + offB[j]);                               \
      i32x4 hi = *(const i32x4*)(buf + (offB[j] ^ 16));                        \
      bf[j] = __builtin_shufflevector(lo, hi, 0, 1, 2, 3, 4, 5, 6, 7);         \
    }                                                                          \
    asm volatile("s_waitcnt lgkmcnt(0)" ::: "memory");                         \
    __builtin_amdgcn_sched_barrier(0);                                         \
    __builtin_amdgcn_s_setprio(1);                                             \
    _Pragma("unroll")                                                          \
    for (int i = 0; i < 4; i++)                                                \
      _Pragma("unroll")                                                        \
      for (int j = 0; j < 2; j++)                                              \
        acc[i][j] = __builtin_amdgcn_mfma_scale_f32_32x32x64_f8f6f4(           \
            af[i], bf[j], acc[i][j], 0, 0, 0, 0x7F7F7F7F, 0, 0x7F7F7F7F);      \
    __builtin_amdgcn_s_setprio(0);                                             \
    __builtin_amdgcn_sched_barrier(0);                                         \
  }

// ---------------- fused S + G pass: one 256x256 tile per block, 8 waves ----------------
// Wave (rw=wv>>2, cw=wv&3) owns rows [rw*128,+128) x cols [cw*64,+64): acc[4][2] of
// 32x32. C/D layout: col = lane&31, row = (reg&3) + 8*(reg>>2) + 4*(lane>>5).
// 64KB LDS + 512 threads -> 2 blocks/CU: same staged volume as R4 (532MB) at 2x the
// per-CU staging rate (the only lever that has moved sg across R0-R6).
__global__ __launch_bounds__(512, 4) void sg_kernel(
    const unsigned char* __restrict__ q1, const unsigned char* __restrict__ q2,
    float* __restrict__ rowS, float* __restrict__ colS,
    float* __restrict__ partG) {
  __shared__ unsigned char lds[2][32768]; // ring-2 x [A 16KB | B 16KB]
  // reductions alias slot 0 (dead after k-loop; guarded by barrier)
  float (*redR)[BM] = reinterpret_cast<float (*)[BM]>(&lds[0][0]);          // [4][256]
  float (*redC)[BM] = reinterpret_cast<float (*)[BM]>(&lds[0][0] + 4096);   // [2][256]

  int bx = blockIdx.x;
  int t = threadIdx.x;
  int lane = t & 63;
  int wv = t >> 6;
  int l31 = lane & 31;
  int h = lane >> 5; // k-half for frags / row-half for C/D
  int rw = wv >> 2;  // 0..1: row half
  int cw = wv & 3;   // 0..3: col quarter
  const float scale = 1.4426950408889634f / 0.04f; // log2(e)/T

  bool smode = bx < S_BLOCKS;
  const unsigned char* X;
  const unsigned char* Y;
  int r0, c0, ga = 0, gb = 0, gg = 0;
  bool diagb = false;
  if (smode) {
    r0 = (bx >> 5) * BM;
    c0 = (bx & 31) * BM;
    X = q1; Y = q2;
  } else {
    int gx = bx - S_BLOCKS;
    gg = (gx >= TRI) ? 1 : 0;
    int tri = gx - gg * TRI;
    int a = (int)((sqrtf(8.0f * (float)tri + 1.0f) - 1.0f) * 0.5f);
    while ((a + 1) * (a + 2) / 2 <= tri) a++;
    while (a * (a + 1) / 2 > tri) a--;
    int b = tri - a * (a + 1) / 2; // b <= a
    ga = a; gb = b;
    X = gg ? q2 : q1; Y = X;
    r0 = a * BM;
    c0 = b * BM;
    diagb = (a == b);
  }

  // fragment LDS byte offsets (R5 zero-conflict swizzle). u,f from l31 only
  // (sub-block bases are multiples of 32 -> swizzle fields reduce to l31 bits).
  // Register slot b of lane holds global k-bytes [(2h+b)*16, +16).
  int u = (l31 >> 4) & 1;
  int f = (l31 >> 1) & 3;
  int cs0 = (h << 1) ^ u ^ f;
  int offA[4], offB[2];
#pragma unroll
  for (int i = 0; i < 4; i++) {
    int rowa = rw * 128 + i * 32 + l31;
    offA[i] = rowa * 64 + cs0 * 16;
  }
#pragma unroll
  for (int j = 0; j < 2; j++) {
    int rowb = cw * 64 + j * 32 + l31;
    offB[j] = 16384 + rowb * 64 + cs0 * 16;
  }

  // staging base pointers: thread t -> row = t>>2 (+128 per pass), dest piece = t&3;
  // src piece = (t&3) ^ ((t>>3)&3) ^ ((t>>6)&1)  (pass-invariant: 128 % 32 == 0)
  int srow = t >> 2;
  int ssrc = (t & 3) ^ ((t >> 3) & 3) ^ ((t >> 6) & 1);
  const unsigned char* pA = X + (size_t)(r0 + srow) * D + ssrc * 16;
  const unsigned char* pB = Y + (size_t)(c0 + srow) * D + ssrc * 16;

  f32x16 acc[4][2];
#pragma unroll
  for (int i = 0; i < 4; i++)
#pragma unroll
    for (int j = 0; j < 2; j++)
#pragma unroll
      for (int r = 0; r < 16; r++) acc[i][j][r] = 0.0f;

  stage_chunk(pA, pB, lds, t, 0);

  SG_ROUND(0) SG_ROUND(1) SG_ROUND(2) SG_ROUND(3)
  SG_ROUND(4) SG_ROUND(5) SG_ROUND(6) SG_ROUND(7)

  __syncthreads(); // ring dead; reuse as reduction scratch

  if (smode) {
    // ---- row + col sums of exp2(scale*g); fixed reference (fits fp32) ----
    float csum[2] = {0.0f, 0.0f};
#pragma unroll
    for (int i = 0; i < 4; i++) {
      float rsum[16];
#pragma unroll
      for (int reg = 0; reg < 16; reg++) rsum[reg] = 0.0f;
#pragma unroll
      for (int j = 0; j < 2; j++)
#pragma unroll
        for (int reg = 0; reg < 16; reg++) {
          float e = __builtin_amdgcn_exp2f(acc[i][j][reg] * scale);
          rsum[reg] += e;
          csum[j] += e;
        }
      // row-sum: reduce across the 32 lanes of this k/row-half (bit5 preserved)
#pragma unroll
      for (int reg = 0; reg < 16; reg++) {
#pragma unroll
        for (int off = 1; off < 32; off <<= 1) rsum[reg] += __shfl_xor(rsum[reg], off);
      }
      if (l31 == 0) {
#pragma unroll
        for (int reg = 0; reg < 16; reg++) {
          int rloc = (reg & 3) + 8 * (reg >> 2) + 4 * h;
          redR[cw][rw * 128 + i * 32 + rloc] = rsum[reg];
        }
      }
    }
    // col-sum: add the other row-half of this wave, then one lane-half writes
#pragma unroll
    for (int j = 0; j < 2; j++) {
      csum[j] += __shfl_xor(csum[j], 32);
      if (h == 0) redC[rw][cw * 64 + j * 32 + l31] = csum[j];
    }
    __syncthreads();
    if (t < BM) {
      rowS[(size_t)(c0 >> 8) * N + r0 + t] =
          redR[0][t] + redR[1][t] + redR[2][t] + redR[3][t];
      colS[(size_t)(r0 >> 8) * N + c0 + t] = redC[0][t] + redC[1][t];
    }
  } else {
    // ---- Gram: row max (strip a), diag-masked; col max = row max of strip b ----
#pragma unroll
    for (int i = 0; i < 4; i++) {
      float rmax[16];
#pragma unroll
      for (int reg = 0; reg < 16; reg++) {
        int rloc = (reg & 3) + 8 * (reg >> 2) + 4 * h;
        int rr = rw * 128 + i * 32 + rloc;
        float v = -3.0e38f;
#pragma unroll
        for (int j = 0; j < 2; j++) {
          float x = acc[i][j][reg];
          int cc = cw * 64 + j * 32 + l31;
          if (diagb && cc == rr) x = -3.0e38f;
          v = fmaxf(v, x);
        }
        rmax[reg] = v;
      }
#pragma unroll
      for (int reg = 0; reg < 16; reg++) {
#pragma unroll
        for (int off = 1; off < 32; off <<= 1) rmax[reg] = fmaxf(rmax[reg], __shfl_xor(rmax[reg], off));
      }
      if (l31 == 0) {
#pragma unroll
        for (int reg = 0; reg < 16; reg++) {
          int rloc = (reg & 3) + 8 * (reg >> 2) + 4 * h;
          redR[cw][rw * 128 + i * 32 + rloc] = rmax[reg];
        }
      }
    }
    if (!diagb) {
#pragma unroll
      for (int j = 0; j < 2; j++) {
        float m = -3.0e38f;
#pragma unroll
        for (int i = 0; i < 4; i++)
#pragma unroll
          for (int reg = 0; reg < 16; reg++) m = fmaxf(m, acc[i][j][reg]);
        m = fmaxf(m, __shfl_xor(m, 32));
        if (h == 0) redC[rw][cw * 64 + j * 32 + l31] = m;
      }
    }
    __syncthreads();
    if (t < BM) {
      partG[((size_t)(gg * NSTRIP + gb)) * N + r0 + t] =
          fmaxf(fmaxf(redR[0][t], redR[1][t]), fmaxf(redR[2][t], redR[3][t]));
      if (!diagb)
        partG[((size_t)(gg * NSTRIP + ga)) * N + c0 + t] = fmaxf(redC[0][t], redC[1][t]);
    }
  }
}

// ---------------- per-row combine of partials -> atomic scalar ----------------
__global__ __launch_bounds__(256) void combine_kernel(
    const float* __restrict__ diag,
    const float* __restrict__ rowS, const float* __restrict__ colS,
    const float* __restrict__ partG, float* __restrict__ out) {
  int t = threadIdx.x;
  int l = t & 63;
  int w = t >> 6;
  int i = blockIdx.x * 64 + l;

  float sR = 0.0f, sC = 0.0f, g1 = -3.0e38f, g2 = -3.0e38f;
#pragma unroll
  for (int s = 0; s < 8; s++) {
    int strip = w * 8 + s;
    sR += rowS[(size_t)strip * N + i];
    sC += colS[(size_t)strip * N + i];
    g1 = fmaxf(g1, partG[(size_t)strip * N + i]);
    g2 = fmaxf(g2, partG[(size_t)(NSTRIP + strip) * N + i]);
  }
  __shared__ float red[4][4][64];
  red[0][w][l] = sR; red[1][w][l] = sC; red[2][w][l] = g1; red[3][w][l] = g2;
  __syncthreads();
  if (w == 0) {
    sR = red[0][0][l] + red[0][1][l] + red[0][2][l] + red[0][3][l];
    sC = red[1][0][l] + red[1][1][l] + red[1][2][l] + red[1][3][l];
    g1 = fmaxf(fmaxf(red[2][0][l], red[2][1][l]), fmaxf(red[2][2][l], red[2][3][l]));
    g2 = fmaxf(fmaxf(red[3][0][l], red[3][1][l]), fmaxf(red[3][2][l], red[3][3][l]));
    float dv = diag[i] * 25.0f;
    float a12 = logf(sR) - dv;
    float a21 = logf(sC) - dv;
    float k1 = logf(sqrtf(fmaxf(2.0f - 2.0f * g1, 0.0f)) + 1e-9f);
    float k2 = logf(sqrtf(fmaxf(2.0f - 2.0f * g2, 0.0f)) + 1e-9f);
    float c = 0.5f * (a12 + a21) / (float)N - 0.1f * 0.5f * (k1 + k2) / (float)N;
#pragma unroll
    for (int off = 1; off < 64; off <<= 1) c += __shfl_xor(c, off);
    if (l == 0) atomicAdd(out, c); // device-scope, out zeroed by norm_kernel
  }
}

extern "C" void kernel_launch(void* const* d_in, const int* in_sizes, int n_in,
                              void* d_out, int out_size, void* d_ws, size_t ws_size,
                              hipStream_t stream) {
  const float* z1 = (const float*)d_in[0];
  const float* z2 = (const float*)d_in[1];
  char* w = (char*)d_ws;
  unsigned char* q1 = (unsigned char*)w; w += (size_t)N * D;
  unsigned char* q2 = (unsigned char*)w; w += (size_t)N * D;
  float* diag = (float*)w;   w += (size_t)N * sizeof(float);
  float* rowS = (float*)w;   w += (size_t)NSTRIP * N * sizeof(float);
  float* colS = (float*)w;   w += (size_t)NSTRIP * N * sizeof(float);
  float* partG = (float*)w;  w += (size_t)2 * NSTRIP * N * sizeof(float);
  float* out = (float*)d_out;

  norm_kernel<<<N / 4, 256, 0, stream>>>(z1, z2, q1, q2, diag, out);
  sg_kernel<<<SG_BLOCKS, 512, 0, stream>>>(q1, q2, rowS, colS, partG);
  combine_kernel<<<N / 64, 256, 0, stream>>>(diag, rowS, colS, partG, out);
}

// Round 8
// 222.294 us; speedup vs baseline: 4.7714x; 4.7714x over previous
//
#include <hip/hip_runtime.h>
#include <hip/hip_bf16.h>
#include <hip/hip_fp8.h>
#include <math.h>

#define N 8192
#define D 512
#define BM 256
#define BK 64
#define NSTRIP 32                       // N / BM
#define S_BLOCKS (NSTRIP * NSTRIP)      // 1024 S tiles
#define TRI (NSTRIP * (NSTRIP + 1) / 2) // 528
#define G_BLOCKS (2 * TRI)              // 1056 Gram tiles
#define SG_BLOCKS (S_BLOCKS + G_BLOCKS) // 2080

typedef float f32x16 __attribute__((ext_vector_type(16)));
typedef int i32x4 __attribute__((ext_vector_type(4)));
typedef int i32x8 __attribute__((ext_vector_type(8)));

__device__ inline void gload_lds16(const void* g, void* l) {
  __builtin_amdgcn_global_load_lds(
      (const __attribute__((address_space(1))) void*)g,
      (__attribute__((address_space(3))) void*)l, 16, 0, 0);
}

// ---------------- normalize to fp8 e4m3 + exact fp32 diagonal + zero out ----------------
__global__ __launch_bounds__(256) void norm_kernel(
    const float* __restrict__ z1, const float* __restrict__ z2,
    unsigned char* __restrict__ q1, unsigned char* __restrict__ q2,
    float* __restrict__ diag, float* __restrict__ out) {
  int t = threadIdx.x;
  int lane = t & 63;
  int w = t >> 6;
  int row = blockIdx.x * 4 + w;
  if (blockIdx.x == 0 && t == 0) out[0] = 0.0f; // atomic target (stream-ordered)
  const float4* a = (const float4*)(z1 + (size_t)row * D);
  const float4* b = (const float4*)(z2 + (size_t)row * D);
  float4 xa0 = a[lane], xa1 = a[lane + 64];
  float4 xb0 = b[lane], xb1 = b[lane + 64];
  float ss1 = xa0.x * xa0.x + xa0.y * xa0.y + xa0.z * xa0.z + xa0.w * xa0.w +
              xa1.x * xa1.x + xa1.y * xa1.y + xa1.z * xa1.z + xa1.w * xa1.w;
  float ss2 = xb0.x * xb0.x + xb0.y * xb0.y + xb0.z * xb0.z + xb0.w * xb0.w +
              xb1.x * xb1.x + xb1.y * xb1.y + xb1.z * xb1.z + xb1.w * xb1.w;
  float dd = xa0.x * xb0.x + xa0.y * xb0.y + xa0.z * xb0.z + xa0.w * xb0.w +
             xa1.x * xb1.x + xa1.y * xb1.y + xa1.z * xb1.z + xa1.w * xb1.w;
#pragma unroll
  for (int off = 1; off < 64; off <<= 1) {
    ss1 += __shfl_xor(ss1, off);
    ss2 += __shfl_xor(ss2, off);
    dd  += __shfl_xor(dd,  off);
  }
  float i1 = 1.0f / fmaxf(sqrtf(ss1), 1e-12f);
  float i2 = 1.0f / fmaxf(sqrtf(ss2), 1e-12f);
  float fa[8] = {xa0.x, xa0.y, xa0.z, xa0.w, xa1.x, xa1.y, xa1.z, xa1.w};
  float fb[8] = {xb0.x, xb0.y, xb0.z, xb0.w, xb1.x, xb1.y, xb1.z, xb1.w};
  unsigned int u1[2], u2[2];
#pragma unroll
  for (int g = 0; g < 2; g++) {
    unsigned int v1 = 0, v2 = 0;
#pragma unroll
    for (int e = 0; e < 4; e++) {
      __hip_fp8_e4m3 c1(fa[g * 4 + e] * i1); // OCP e4m3fn
      __hip_fp8_e4m3 c2(fb[g * 4 + e] * i2);
      v1 |= ((unsigned int)c1.__x) << (8 * e);
      v2 |= ((unsigned int)c2.__x) << (8 * e);
    }
    u1[g] = v1; u2[g] = v2;
  }
  ((unsigned int*)q1)[(size_t)row * 128 + lane] = u1[0];
  ((unsigned int*)q1)[(size_t)row * 128 + 64 + lane] = u1[1];
  ((unsigned int*)q2)[(size_t)row * 128 + lane] = u2[0];
  ((unsigned int*)q2)[(size_t)row * 128 + 64 + lane] = u2[1];
  if (lane == 0) diag[row] = dd * i1 * i2;
}

// ---------------- stage ONE quarter (8KB) of a BK=64 chunk into ring slot chunk&3 -----
// R5/R7 zero-conflict swizzle folded into per-thread global base (pA/pB); quarter
// q in {A-low, A-high, B-low, B-high}. One gload_lds per thread per quarter.
__device__ __forceinline__ void stage_quarter(
    const unsigned char* pA, const unsigned char* pB,
    unsigned char* lds, int t, int chunk, int q) {
  unsigned char* buf = lds + (size_t)(chunk & 3) * 32768;
  int k0 = chunk * BK;
  if (q == 0)      gload_lds16(pA + k0,           buf + t * 16);
  else if (q == 1) gload_lds16(pA + 128 * D + k0, buf + 8192 + t * 16);
  else if (q == 2) gload_lds16(pB + k0,           buf + 16384 + t * 16);
  else             gload_lds16(pB + 128 * D + k0, buf + 24576 + t * 16);
}

#define VM_WAIT(n) asm volatile("s_waitcnt vmcnt(" #n ")" ::: "memory")

// ---------------- m201-style fine-interleaved phase -----------------------------------
// Phase (p,q): {ds_read af[q] (+bf pair at q==0) from slot p&3; issue stage quarter q
// of chunk p+2 into slot (p+2)&3; [tail vmcnt at q==3]; barrier; lgkmcnt(0)+SB;
// setprio(1); 2 MFMA; setprio(0); barrier}.
// vmcnt(4) once per step keeps chunk p+2's 4 loads in flight ACROSS barriers (T3/T4);
// never drains to 0 mid-loop. Slot safety: slot (p+2)&3 last read in step p-2,
// ordered by that step's phase barriers; chunk p (slot p&3) was staged in step p-2
// and vmcnt-drained before step p-1's tail barrier.
#define SG_PHASE(p, q, DOSTAGE, VMTAIL)                                        \
  {                                                                            \
    const unsigned char* buf = lds + (size_t)((p) & 3) * 32768;                \
    i32x4 lo = *(const i32x4*)(buf + offA[q]);                                 \
    i32x4 hi = *(const i32x4*)(buf + (offA[q] ^ 16));                          \
    i32x8 af = __builtin_shufflevector(lo, hi, 0, 1, 2, 3, 4, 5, 6, 7);        \
    if ((q) == 0) {                                                            \
      i32x4 l0 = *(const i32x4*)(buf + offB[0]);                               \
      i32x4 h0 = *(const i32x4*)(buf + (offB[0] ^ 16));                        \
      bf0 = __builtin_shufflevector(l0, h0, 0, 1, 2, 3, 4, 5, 6, 7);           \
      i32x4 l1 = *(const i32x4*)(buf + offB[1]);                               \
      i32x4 h1 = *(const i32x4*)(buf + (offB[1] ^ 16));                        \
      bf1 = __builtin_shufflevector(l1, h1, 0, 1, 2, 3, 4, 5, 6, 7);           \
    }                                                                          \
    if (DOSTAGE) stage_quarter(pA, pB, lds, t, (p) + 2, q);                    \
    VMTAIL;                                                                    \
    __builtin_amdgcn_s_barrier();                                              \
    asm volatile("s_waitcnt lgkmcnt(0)" ::: "memory");                         \
    __builtin_amdgcn_sched_barrier(0);                                         \
    __builtin_amdgcn_s_setprio(1);                                             \
    acc[q][0] = __builtin_amdgcn_mfma_scale_f32_32x32x64_f8f6f4(               \
        af, bf0, acc[q][0], 0, 0, 0, 0x7F7F7F7F, 0, 0x7F7F7F7F);               \
    acc[q][1] = __builtin_amdgcn_mfma_scale_f32_32x32x64_f8f6f4(               \
        af, bf1, acc[q][1], 0, 0, 0, 0x7F7F7F7F, 0, 0x7F7F7F7F);               \
    __builtin_amdgcn_s_setprio(0);                                             \
    __builtin_amdgcn_sched_barrier(0);                                         \
    __builtin_amdgcn_s_barrier();                                              \
  }

#define SG_STEP(p, DOSTAGE, VMTAIL)                                            \
  SG_PHASE(p, 0, DOSTAGE, ;)                                                   \
  SG_PHASE(p, 1, DOSTAGE, ;)                                                   \
  SG_PHASE(p, 2, DOSTAGE, ;)                                                   \
  SG_PHASE(p, 3, DOSTAGE, VMTAIL)

// ---------------- fused S + G pass: one 256x256 tile per block, 8 waves ----------------
// Wave (rw=wv>>2, cw=wv&3) owns rows [rw*128,+128) x cols [cw*64,+64): acc[4][2] of
// 32x32. C/D layout: col = lane&31, row = (reg&3) + 8*(reg>>2) + 4*(lane>>5).
// 1 block/CU (128 KB LDS, ~236 unified regs); __launch_bounds__(512,2) -- R7's (512,4)
// forced a 128-reg cap and spilled acc (4.7 GB scratch traffic).
__global__ __launch_bounds__(512, 2) void sg_kernel(
    const unsigned char* __restrict__ q1, const unsigned char* __restrict__ q2,
    float* __restrict__ rowS, float* __restrict__ colS,
    float* __restrict__ partG) {
  extern __shared__ unsigned char lds[]; // ring-4 x [A 16KB | B 16KB] = 128 KB
  // reductions alias slot 0 (dead after k-loop; guarded by __syncthreads)
  float (*redR)[BM] = reinterpret_cast<float (*)[BM]>(&lds[0]);          // [4][256]
  float (*redC)[BM] = reinterpret_cast<float (*)[BM]>(&lds[0] + 4096);   // [2][256]

  int bx = blockIdx.x;
  int t = threadIdx.x;
  int lane = t & 63;
  int wv = t >> 6;
  int l31 = lane & 31;
  int h = lane >> 5; // k-half for frags / row-half for C/D
  int rw = wv >> 2;  // 0..1: row half
  int cw = wv & 3;   // 0..3: col quarter
  const float scale = 1.4426950408889634f / 0.04f; // log2(e)/T

  bool smode = bx < S_BLOCKS;
  const unsigned char* X;
  const unsigned char* Y;
  int r0, c0, ga = 0, gb = 0, gg = 0;
  bool diagb = false;
  if (smode) {
    r0 = (bx >> 5) * BM;
    c0 = (bx & 31) * BM;
    X = q1; Y = q2;
  } else {
    int gx = bx - S_BLOCKS;
    gg = (gx >= TRI) ? 1 : 0;
    int tri = gx - gg * TRI;
    int a = (int)((sqrtf(8.0f * (float)tri + 1.0f) - 1.0f) * 0.5f);
    while ((a + 1) * (a + 2) / 2 <= tri) a++;
    while (a * (a + 1) / 2 > tri) a--;
    int b = tri - a * (a + 1) / 2; // b <= a
    ga = a; gb = b;
    X = gg ? q2 : q1; Y = X;
    r0 = a * BM;
    c0 = b * BM;
    diagb = (a == b);
  }

  // fragment LDS byte offsets (R5/R7 zero-conflict swizzle; verified absmax 0.0).
  // Register slot b of lane holds global k-bytes [(2h+b)*16, +16).
  int u = (l31 >> 4) & 1;
  int f = (l31 >> 1) & 3;
  int cs0 = (h << 1) ^ u ^ f;
  int offA[4], offB[2];
#pragma unroll
  for (int i = 0; i < 4; i++) {
    int rowa = rw * 128 + i * 32 + l31;
    offA[i] = rowa * 64 + cs0 * 16;
  }
#pragma unroll
  for (int j = 0; j < 2; j++) {
    int rowb = cw * 64 + j * 32 + l31;
    offB[j] = 16384 + rowb * 64 + cs0 * 16;
  }

  // staging base pointers: thread t -> row = t>>2 (+128 for high half), piece = t&3;
  // src piece = (t&3) ^ ((t>>3)&3) ^ ((t>>6)&1)  (row+128 preserves both fields)
  int srow = t >> 2;
  int ssrc = (t & 3) ^ ((t >> 3) & 3) ^ ((t >> 6) & 1);
  const unsigned char* pA = X + (size_t)(r0 + srow) * D + ssrc * 16;
  const unsigned char* pB = Y + (size_t)(c0 + srow) * D + ssrc * 16;

  f32x16 acc[4][2];
#pragma unroll
  for (int i = 0; i < 4; i++)
#pragma unroll
    for (int j = 0; j < 2; j++)
#pragma unroll
      for (int r = 0; r < 16; r++) acc[i][j][r] = 0.0f;

  // prologue: fully stage chunks 0 and 1; drain chunk 0, keep chunk 1 in flight
#pragma unroll
  for (int q = 0; q < 4; q++) stage_quarter(pA, pB, lds, t, 0, q);
#pragma unroll
  for (int q = 0; q < 4; q++) stage_quarter(pA, pB, lds, t, 1, q);
  VM_WAIT(4);
  __builtin_amdgcn_s_barrier();

  i32x8 bf0, bf1;
  SG_STEP(0, 1, VM_WAIT(4))
  SG_STEP(1, 1, VM_WAIT(4))
  SG_STEP(2, 1, VM_WAIT(4))
  SG_STEP(3, 1, VM_WAIT(4))
  SG_STEP(4, 1, VM_WAIT(4))
  SG_STEP(5, 1, VM_WAIT(4))
  SG_STEP(6, 0, VM_WAIT(0))
  SG_STEP(7, 0, ;)

  __syncthreads(); // ring dead; reuse as reduction scratch

  if (smode) {
    // ---- row + col sums of exp2(scale*g); fixed reference (fits fp32) ----
    float csum[2] = {0.0f, 0.0f};
#pragma unroll
    for (int i = 0; i < 4; i++) {
      float rsum[16];
#pragma unroll
      for (int reg = 0; reg < 16; reg++) rsum[reg] = 0.0f;
#pragma unroll
      for (int j = 0; j < 2; j++)
#pragma unroll
        for (int reg = 0; reg < 16; reg++) {
          float e = __builtin_amdgcn_exp2f(acc[i][j][reg] * scale);
          rsum[reg] += e;
          csum[j] += e;
        }
      // row-sum: reduce across the 32 lanes of this k/row-half (bit5 preserved)
#pragma unroll
      for (int reg = 0; reg < 16; reg++) {
#pragma unroll
        for (int off = 1; off < 32; off <<= 1) rsum[reg] += __shfl_xor(rsum[reg], off);
      }
      if (l31 == 0) {
#pragma unroll
        for (int reg = 0; reg < 16; reg++) {
          int rloc = (reg & 3) + 8 * (reg >> 2) + 4 * h;
          redR[cw][rw * 128 + i * 32 + rloc] = rsum[reg];
        }
      }
    }
    // col-sum: add the other row-half of this wave, then one lane-half writes
#pragma unroll
    for (int j = 0; j < 2; j++) {
      csum[j] += __shfl_xor(csum[j], 32);
      if (h == 0) redC[rw][cw * 64 + j * 32 + l31] = csum[j];
    }
    __syncthreads();
    if (t < BM) {
      rowS[(size_t)(c0 >> 8) * N + r0 + t] =
          redR[0][t] + redR[1][t] + redR[2][t] + redR[3][t];
      colS[(size_t)(r0 >> 8) * N + c0 + t] = redC[0][t] + redC[1][t];
    }
  } else {
    // ---- Gram: row max (strip a), diag-masked; col max = row max of strip b ----
#pragma unroll
    for (int i = 0; i < 4; i++) {
      float rmax[16];
#pragma unroll
      for (int reg = 0; reg < 16; reg++) {
        int rloc = (reg & 3) + 8 * (reg >> 2) + 4 * h;
        int rr = rw * 128 + i * 32 + rloc;
        float v = -3.0e38f;
#pragma unroll
        for (int j = 0; j < 2; j++) {
          float x = acc[i][j][reg];
          int cc = cw * 64 + j * 32 + l31;
          if (diagb && cc == rr) x = -3.0e38f;
          v = fmaxf(v, x);
        }
        rmax[reg] = v;
      }
#pragma unroll
      for (int reg = 0; reg < 16; reg++) {
#pragma unroll
        for (int off = 1; off < 32; off <<= 1) rmax[reg] = fmaxf(rmax[reg], __shfl_xor(rmax[reg], off));
      }
      if (l31 == 0) {
#pragma unroll
        for (int reg = 0; reg < 16; reg++) {
          int rloc = (reg & 3) + 8 * (reg >> 2) + 4 * h;
          redR[cw][rw * 128 + i * 32 + rloc] = rmax[reg];
        }
      }
    }
    if (!diagb) {
#pragma unroll
      for (int j = 0; j < 2; j++) {
        float m = -3.0e38f;
#pragma unroll
        for (int i = 0; i < 4; i++)
#pragma unroll
          for (int reg = 0; reg < 16; reg++) m = fmaxf(m, acc[i][j][reg]);
        m = fmaxf(m, __shfl_xor(m, 32));
        if (h == 0) redC[rw][cw * 64 + j * 32 + l31] = m;
      }
    }
    __syncthreads();
    if (t < BM) {
      partG[((size_t)(gg * NSTRIP + gb)) * N + r0 + t] =
          fmaxf(fmaxf(redR[0][t], redR[1][t]), fmaxf(redR[2][t], redR[3][t]));
      if (!diagb)
        partG[((size_t)(gg * NSTRIP + ga)) * N + c0 + t] = fmaxf(redC[0][t], redC[1][t]);
    }
  }
}

// ---------------- per-row combine of partials -> atomic scalar ----------------
__global__ __launch_bounds__(256) void combine_kernel(
    const float* __restrict__ diag,
    const float* __restrict__ rowS, const float* __restrict__ colS,
    const float* __restrict__ partG, float* __restrict__ out) {
  int t = threadIdx.x;
  int l = t & 63;
  int w = t >> 6;
  int i = blockIdx.x * 64 + l;

  float sR = 0.0f, sC = 0.0f, g1 = -3.0e38f, g2 = -3.0e38f;
#pragma unroll
  for (int s = 0; s < 8; s++) {
    int strip = w * 8 + s;
    sR += rowS[(size_t)strip * N + i];
    sC += colS[(size_t)strip * N + i];
    g1 = fmaxf(g1, partG[(size_t)strip * N + i]);
    g2 = fmaxf(g2, partG[(size_t)(NSTRIP + strip) * N + i]);
  }
  __shared__ float red[4][4][64];
  red[0][w][l] = sR; red[1][w][l] = sC; red[2][w][l] = g1; red[3][w][l] = g2;
  __syncthreads();
  if (w == 0) {
    sR = red[0][0][l] + red[0][1][l] + red[0][2][l] + red[0][3][l];
    sC = red[1][0][l] + red[1][1][l] + red[1][2][l] + red[1][3][l];
    g1 = fmaxf(fmaxf(red[2][0][l], red[2][1][l]), fmaxf(red[2][2][l], red[2][3][l]));
    g2 = fmaxf(fmaxf(red[3][0][l], red[3][1][l]), fmaxf(red[3][2][l], red[3][3][l]));
    float dv = diag[i] * 25.0f;
    float a12 = logf(sR) - dv;
    float a21 = logf(sC) - dv;
    float k1 = logf(sqrtf(fmaxf(2.0f - 2.0f * g1, 0.0f)) + 1e-9f);
    float k2 = logf(sqrtf(fmaxf(2.0f - 2.0f * g2, 0.0f)) + 1e-9f);
    float c = 0.5f * (a12 + a21) / (float)N - 0.1f * 0.5f * (k1 + k2) / (float)N;
#pragma unroll
    for (int off = 1; off < 64; off <<= 1) c += __shfl_xor(c, off);
    if (l == 0) atomicAdd(out, c); // device-scope, out zeroed by norm_kernel
  }
}

extern "C" void kernel_launch(void* const* d_in, const int* in_sizes, int n_in,
                              void* d_out, int out_size, void* d_ws, size_t ws_size,
                              hipStream_t stream) {
  const float* z1 = (const float*)d_in[0];
  const float* z2 = (const float*)d_in[1];
  char* w = (char*)d_ws;
  unsigned char* q1 = (unsigned char*)w; w += (size_t)N * D;
  unsigned char* q2 = (unsigned char*)w; w += (size_t)N * D;
  float* diag = (float*)w;   w += (size_t)N * sizeof(float);
  float* rowS = (float*)w;   w += (size_t)NSTRIP * N * sizeof(float);
  float* colS = (float*)w;   w += (size_t)NSTRIP * N * sizeof(float);
  float* partG = (float*)w;  w += (size_t)2 * NSTRIP * N * sizeof(float);
  float* out = (float*)d_out;

  static bool attr_done = false;
  if (!attr_done) {
    hipFuncSetAttribute((const void*)sg_kernel,
                        hipFuncAttributeMaxDynamicSharedMemorySize, 131072);
    attr_done = true;
  }

  norm_kernel<<<N / 4, 256, 0, stream>>>(z1, z2, q1, q2, diag, out);
  sg_kernel<<<SG_BLOCKS, 512, 131072, stream>>>(q1, q2, rowS, colS, partG);
  combine_kernel<<<N / 64, 256, 0, stream>>>(diag, rowS, colS, partG, out);
}